// Round 3
// baseline (311.524 us; speedup 1.0000x reference)
//
#include <hip/hip_runtime.h>
#include <cstdint>

#define Bq 16
#define Nq 512
#define Dq 12
#define HID 32
#define HEADS 4
#define Cq 8
#define NR 36   // 4 lsum rows + 32 acc rows

// ws layout (float offsets)
#define OFF_G     0u         // [b][n][32]       262144
#define OFF_AS    262144u    // [b][n][4]         32768
#define OFF_AD    294912u    // [b][n][4]         32768
#define OFF_TI    327680u    // [b][n][32]       262144
#define OFF_TJB   589824u    // [b][h][j]        262144
#define OFF_PACK  851968u    // u64 [b][i][8]    131072 floats (byte off %8==0)
#define OFF_RED   983040u    // [b][r=36][j]     294912
#define OFF_PART  1277952u   // [p][b][r=36][j]  P*294912

// ---- k0: per-node h, g, a_s, a_d. 8 nodes/block, thread=(node_sub, k). ----
__global__ __launch_bounds__(256) void k0_node(
    const float* __restrict__ x, const float* __restrict__ Wp, const float* __restrict__ bp,
    const float* __restrict__ Wg, const float* __restrict__ att_src,
    const float* __restrict__ att_dst, float* __restrict__ ws) {
    __shared__ float xs[8 * Dq];
    __shared__ float hs[8][HID];
    int n_sub = threadIdx.x >> 5;
    int k = threadIdx.x & 31;
    int node0 = blockIdx.x * 8;
    if (threadIdx.x < 8 * Dq) xs[threadIdx.x] = x[(size_t)node0 * Dq + threadIdx.x];
    __syncthreads();
    float s = bp[k];
#pragma unroll
    for (int d = 0; d < Dq; d++) s = fmaf(Wp[k * Dq + d], xs[n_sub * Dq + d], s);
    hs[n_sub][k] = s > 0.f ? s : 0.f;
    __syncthreads();
    float g = 0.f;
#pragma unroll
    for (int d = 0; d < HID; d++) g = fmaf(Wg[k * HID + d], hs[n_sub][d], g);
    int nid = node0 + n_sub;
    ws[OFF_G + (size_t)nid * HID + k] = g;
    float ss = g * att_src[k];   // att_src[h][c], k = h*8+c
    float sd = g * att_dst[k];
#pragma unroll
    for (int off = 1; off < 8; off <<= 1) {
        ss += __shfl_xor(ss, off);
        sd += __shfl_xor(sd, off);
    }
    if ((k & 7) == 0) {
        int h = k >> 3;
        ws[OFF_AS + (size_t)nid * HEADS + h] = ss;
        ws[OFF_AD + (size_t)nid * HEADS + h] = sd;
    }
}

// ---- k1: aggregation partials, NO atomics. grid (P, 2, Bq), block 256. ----
template <int ICH>
__global__ __launch_bounds__(256, 4) void k1_aggregate(const int* __restrict__ adj,
                                                       float* __restrict__ ws) {
    constexpr int NCH = ICH / 8;
    int b = blockIdx.z;
    int p = blockIdx.x;
    int j = blockIdx.y * 256 + threadIdx.x;
    int i0 = p * ICH;
    __shared__ float gs[ICH * HID];
    __shared__ float ass[ICH * HEADS];
    {
        const float* gsrc = ws + OFF_G + ((size_t)b * Nq + i0) * HID;
        for (int t = threadIdx.x; t < ICH * HID; t += 256) gs[t] = gsrc[t];
        const float* asrc = ws + OFF_AS + ((size_t)b * Nq + i0) * HEADS;
        for (int t = threadIdx.x; t < ICH * HEADS; t += 256) ass[t] = asrc[t];
    }
    float adv[HEADS];
#pragma unroll
    for (int h = 0; h < HEADS; h++) adv[h] = ws[OFF_AD + ((size_t)b * Nq + j) * HEADS + h];
    __syncthreads();

    uint64_t* packed = (uint64_t*)(ws + OFF_PACK);
    const int* arow = adj + ((size_t)b * Nq + i0) * Nq + j;
    float lsum[HEADS] = {};
    float acc[HEADS][Cq] = {};
    int cur[8], nxt[8];
#pragma unroll
    for (int k = 0; k < 8; k++) cur[k] = arow[(size_t)k * Nq];
    for (int c = 0; c < NCH; c++) {
        if (c + 1 < NCH) {
#pragma unroll
            for (int k = 0; k < 8; k++) nxt[k] = arow[(size_t)((c + 1) * 8 + k) * Nq];
        }
#pragma unroll
        for (int k = 0; k < 8; k++) {
            int ii = c * 8 + k;
            int i = i0 + ii;
            unsigned long long m = __ballot(cur[k] != 0);
            if ((threadIdx.x & 63) == 0)
                packed[((size_t)b * Nq + i) * (Nq / 64) + (j >> 6)] = m;
            bool msk = (cur[k] != 0) || (i == j);
#pragma unroll
            for (int h = 0; h < HEADS; h++) {
                float z = ass[ii * HEADS + h] + adv[h];
                float lk = z > 0.f ? z : 0.2f * z;
                float e = msk ? __expf(lk) : 0.f;  // no max-shift: |z| small
                lsum[h] += e;
#pragma unroll
                for (int cc = 0; cc < Cq; cc++)
                    acc[h][cc] = fmaf(e, gs[ii * HID + h * Cq + cc], acc[h][cc]);
            }
        }
#pragma unroll
        for (int k = 0; k < 8; k++) cur[k] = nxt[k];
    }
    // coalesced partial stores: [p][b][r][j]
    float* pb = ws + OFF_PART + ((size_t)(p * Bq + b) * NR) * Nq + j;
#pragma unroll
    for (int h = 0; h < HEADS; h++) pb[(size_t)h * Nq] = lsum[h];
#pragma unroll
    for (int h = 0; h < HEADS; h++)
#pragma unroll
        for (int cc = 0; cc < Cq; cc++)
            pb[(size_t)(HEADS + h * Cq + cc) * Nq] = acc[h][cc];
}

// ---- k2a: reduce P partials -> [b][r][j]. ----
template <int P>
__global__ __launch_bounds__(256) void k2a_reduce(float* __restrict__ ws) {
    int o = blockIdx.x * 256 + threadIdx.x;  // < Bq*NR*Nq = 294912
    const float* part = ws + OFF_PART + o;
    float s = 0.f;
#pragma unroll
    for (int p = 0; p < P; p++) s += part[(size_t)p * (Bq * NR * Nq)];
    ws[OFF_RED + o] = s;
}

// ---- k2b: hg = acc/lsum + bias; ti = hg·W1i; tjb = hg·W1j + b1 (transposed). ----
__global__ __launch_bounds__(128) void k2b_finalize(const float* __restrict__ bias_g,
                                                    const float* __restrict__ W1,
                                                    const float* __restrict__ b1,
                                                    float* __restrict__ ws) {
    int nid = blockIdx.x * 128 + threadIdx.x;
    int b = nid >> 9, j = nid & (Nq - 1);
    const float* red = ws + OFF_RED + (size_t)b * NR * Nq + j;
    float inv[HEADS];
#pragma unroll
    for (int h = 0; h < HEADS; h++) inv[h] = __builtin_amdgcn_rcpf(red[(size_t)h * Nq]);
    float hg[HID];
#pragma unroll
    for (int r = 0; r < HID; r++)
        hg[r] = red[(size_t)(HEADS + r) * Nq] * inv[r >> 3] + bias_g[r];
#pragma unroll
    for (int h = 0; h < HID; h++) {
        float si = 0.f, sj = 0.f;
#pragma unroll
        for (int d = 0; d < HID; d++) {
            si = fmaf(hg[d], W1[h * 2 * HID + d], si);
            sj = fmaf(hg[d], W1[h * 2 * HID + HID + d], sj);
        }
        ws[OFF_TI + (size_t)nid * HID + h] = si;
        ws[OFF_TJB + ((size_t)b * HID + h) * Nq + j] = sj + b1[h];
    }
}

// ---- k3: pairwise score. grid (32, Bq), block 512. ----
__global__ __launch_bounds__(512, 4) void k3_score(const float* __restrict__ w2_p,
                                                   const float* __restrict__ b2_p,
                                                   const float* __restrict__ ws,
                                                   float* __restrict__ out) {
    int b = blockIdx.y;
    int i0 = blockIdx.x * 16;
    int j = threadIdx.x;
    __shared__ float tis[16 * HID];
    tis[threadIdx.x] = ws[OFF_TI + ((size_t)b * Nq + i0) * HID + threadIdx.x];
    float tjb[HID];
#pragma unroll
    for (int h = 0; h < HID; h++) tjb[h] = ws[OFF_TJB + ((size_t)b * HID + h) * Nq + j];
    float w2l[HID];
#pragma unroll
    for (int h = 0; h < HID; h++) w2l[h] = w2_p[h];
    float b2 = b2_p[0];
    __syncthreads();
    const uint64_t* packed = (const uint64_t*)(ws + OFF_PACK);
    for (int ii = 0; ii < 16; ii++) {
        int i = i0 + ii;
        uint64_t m = packed[((size_t)b * Nq + i) * (Nq / 64) + (j >> 6)];
        bool on = (((m >> (j & 63)) & 1ull) != 0) && (i != j);
        float s = b2;
#pragma unroll
        for (int h = 0; h < HID; h++) {
            float t = tis[ii * HID + h] + tjb[h];
            t = t > 0.f ? t : 0.f;
            s = fmaf(t, w2l[h], s);
        }
        float score = __builtin_amdgcn_rcpf(1.f + __expf(-s));
        out[((size_t)b * Nq + i) * Nq + j] = on ? score : 0.f;
    }
}

extern "C" void kernel_launch(void* const* d_in, const int* in_sizes, int n_in,
                              void* d_out, int out_size, void* d_ws, size_t ws_size,
                              hipStream_t stream) {
    const float* x       = (const float*)d_in[0];
    const int*   adj     = (const int*)d_in[1];
    const float* Wp      = (const float*)d_in[2];
    const float* bp      = (const float*)d_in[3];
    const float* Wg      = (const float*)d_in[4];
    const float* att_src = (const float*)d_in[5];
    const float* att_dst = (const float*)d_in[6];
    const float* bias_g  = (const float*)d_in[7];
    const float* W1      = (const float*)d_in[8];
    const float* b1      = (const float*)d_in[9];
    const float* w2      = (const float*)d_in[10];
    const float* b2      = (const float*)d_in[11];
    float* out = (float*)d_out;
    float* ws = (float*)d_ws;

    auto need = [](int P) {
        return (size_t)(OFF_PART + (size_t)P * Bq * NR * Nq) * sizeof(float);
    };

    k0_node<<<dim3(1024), dim3(256), 0, stream>>>(x, Wp, bp, Wg, att_src, att_dst, ws);

    if (ws_size >= need(16)) {
        k1_aggregate<32><<<dim3(16, 2, Bq), dim3(256), 0, stream>>>(adj, ws);
        k2a_reduce<16><<<dim3(1152), dim3(256), 0, stream>>>(ws);
    } else if (ws_size >= need(8)) {
        k1_aggregate<64><<<dim3(8, 2, Bq), dim3(256), 0, stream>>>(adj, ws);
        k2a_reduce<8><<<dim3(1152), dim3(256), 0, stream>>>(ws);
    } else if (ws_size >= need(4)) {
        k1_aggregate<128><<<dim3(4, 2, Bq), dim3(256), 0, stream>>>(adj, ws);
        k2a_reduce<4><<<dim3(1152), dim3(256), 0, stream>>>(ws);
    } else {
        k1_aggregate<256><<<dim3(2, 2, Bq), dim3(256), 0, stream>>>(adj, ws);
        k2a_reduce<2><<<dim3(1152), dim3(256), 0, stream>>>(ws);
    }

    k2b_finalize<<<dim3(64), dim3(128), 0, stream>>>(bias_g, W1, b1, ws);
    k3_score<<<dim3(32, Bq), dim3(512), 0, stream>>>(w2, b2, ws, out);
}

// Round 4
// 152.246 us; speedup vs baseline: 2.0462x; 2.0462x over previous
//
#include <hip/hip_runtime.h>
#include <cstdint>

#define Bq 16
#define Nq 512
#define Dq 12
#define HID 32
#define HEADS 4
#define Cq 8
#define NR 36   // 4 lsum rows + 32 acc rows

// ws layout (float offsets)
#define OFF_G     0u         // [b][n][32]       262144
#define OFF_AS    262144u    // [b][n][4]         32768
#define OFF_AD    294912u    // [b][n][4]         32768
#define OFF_TIT   327680u    // [b][h][n]        262144  (ti TRANSPOSED)
#define OFF_TJB   589824u    // [b][h][n]        262144
#define OFF_PACK  851968u    // u64 [b][i][8]    131072 floats (byte off %8==0)
#define OFF_PART  983040u    // [p][b][r=36][n]  P*294912

// ---- k0: per-node h, g, a_s, a_d. 8 nodes/block. ----
__global__ __launch_bounds__(256) void k0_node(
    const float* __restrict__ x, const float* __restrict__ Wp, const float* __restrict__ bp,
    const float* __restrict__ Wg, const float* __restrict__ att_src,
    const float* __restrict__ att_dst, float* __restrict__ ws) {
    __shared__ float xs[8 * Dq];
    __shared__ float hs[8][HID];
    int n_sub = threadIdx.x >> 5;
    int k = threadIdx.x & 31;
    int node0 = blockIdx.x * 8;
    if (threadIdx.x < 8 * Dq) xs[threadIdx.x] = x[(size_t)node0 * Dq + threadIdx.x];
    __syncthreads();
    float s = bp[k];
#pragma unroll
    for (int d = 0; d < Dq; d++) s = fmaf(Wp[k * Dq + d], xs[n_sub * Dq + d], s);
    hs[n_sub][k] = s > 0.f ? s : 0.f;
    __syncthreads();
    float g = 0.f;
#pragma unroll
    for (int d = 0; d < HID; d++) g = fmaf(Wg[k * HID + d], hs[n_sub][d], g);
    int nid = node0 + n_sub;
    ws[OFF_G + (size_t)nid * HID + k] = g;
    float ss = g * att_src[k];   // k = h*8+c
    float sd = g * att_dst[k];
#pragma unroll
    for (int off = 1; off < 8; off <<= 1) {
        ss += __shfl_xor(ss, off);
        sd += __shfl_xor(sd, off);
    }
    if ((k & 7) == 0) {
        int h = k >> 3;
        ws[OFF_AS + (size_t)nid * HEADS + h] = ss;
        ws[OFF_AD + (size_t)nid * HEADS + h] = sd;
    }
}

// ---- k1: aggregation partials, NO atomics, NO min-waves bound (spill!). ----
// grid (P, 2, Bq), block 256. Thread owns j, loops ICH i's.
template <int ICH>
__global__ __launch_bounds__(256) void k1_aggregate(const int* __restrict__ adj,
                                                    float* __restrict__ ws) {
    constexpr int NCH = ICH / 8;
    int b = blockIdx.z;
    int p = blockIdx.x;
    int j = blockIdx.y * 256 + threadIdx.x;
    int i0 = p * ICH;
    __shared__ float gs[ICH * HID];
    __shared__ float ass[ICH * HEADS];
    {
        const float* gsrc = ws + OFF_G + ((size_t)b * Nq + i0) * HID;
        for (int t = threadIdx.x; t < ICH * HID; t += 256) gs[t] = gsrc[t];
        const float* asrc = ws + OFF_AS + ((size_t)b * Nq + i0) * HEADS;
        for (int t = threadIdx.x; t < ICH * HEADS; t += 256) ass[t] = asrc[t];
    }
    float adv[HEADS];
#pragma unroll
    for (int h = 0; h < HEADS; h++) adv[h] = ws[OFF_AD + ((size_t)b * Nq + j) * HEADS + h];
    __syncthreads();

    uint64_t* packed = (uint64_t*)(ws + OFF_PACK);
    const int* arow = adj + ((size_t)b * Nq + i0) * Nq + j;
    float lsum[HEADS] = {};
    float acc[HEADS][Cq] = {};
    int cur[8], nxt[8];
#pragma unroll
    for (int k = 0; k < 8; k++) cur[k] = arow[(size_t)k * Nq];
    for (int c = 0; c < NCH; c++) {
        if (c + 1 < NCH) {
#pragma unroll
            for (int k = 0; k < 8; k++) nxt[k] = arow[(size_t)((c + 1) * 8 + k) * Nq];
        }
#pragma unroll
        for (int k = 0; k < 8; k++) {
            int ii = c * 8 + k;
            int i = i0 + ii;
            unsigned long long m = __ballot(cur[k] != 0);
            if ((threadIdx.x & 63) == 0)
                packed[((size_t)b * Nq + i) * (Nq / 64) + (j >> 6)] = m;
            bool msk = (cur[k] != 0) || (i == j);
#pragma unroll
            for (int h = 0; h < HEADS; h++) {
                float z = ass[ii * HEADS + h] + adv[h];
                float lk = z > 0.f ? z : 0.2f * z;
                float e = msk ? __expf(lk) : 0.f;  // no max-shift: |z| small
                lsum[h] += e;
#pragma unroll
                for (int cc = 0; cc < Cq; cc++)
                    acc[h][cc] = fmaf(e, gs[ii * HID + h * Cq + cc], acc[h][cc]);
            }
        }
#pragma unroll
        for (int k = 0; k < 8; k++) cur[k] = nxt[k];
    }
    float* pb = ws + OFF_PART + ((size_t)(p * Bq + b) * NR) * Nq + j;
#pragma unroll
    for (int h = 0; h < HEADS; h++) pb[(size_t)h * Nq] = lsum[h];
#pragma unroll
    for (int h = 0; h < HEADS; h++)
#pragma unroll
        for (int cc = 0; cc < Cq; cc++)
            pb[(size_t)(HEADS + h * Cq + cc) * Nq] = acc[h][cc];
}

// ---- k2 fused: reduce P partials + hg + ti/tjb (both stored [b][h][n]). ----
// grid (8 j-tiles of 64, Bq), block 256.
template <int P>
__global__ __launch_bounds__(256) void k2_fused(const float* __restrict__ bias_g,
                                                const float* __restrict__ W1,
                                                const float* __restrict__ b1,
                                                float* __restrict__ ws) {
    int b = blockIdx.y;
    int j0 = blockIdx.x * 64;
    int t = threadIdx.x;
    int jl = t & 63;
    int tg = t >> 6;  // 0..3
    __shared__ float red_s[NR * 64];  // 9 KB
    // phase A: sum partials (coalesced: 64 consecutive j per row)
#pragma unroll
    for (int k = 0; k < 9; k++) {
        int r = tg + k * 4;  // covers 0..35
        const float* src = ws + OFF_PART + ((size_t)b * NR + r) * Nq + j0 + jl;
        float s = 0.f;
#pragma unroll
        for (int p = 0; p < P; p++) s += src[(size_t)p * (Bq * NR * Nq)];
        red_s[r * 64 + jl] = s;
    }
    __syncthreads();
    // phase B: hg in regs, 8 heads' worth of W1 dots per thread
    int n = j0 + jl;
    float inv[HEADS];
#pragma unroll
    for (int h = 0; h < HEADS; h++) inv[h] = __builtin_amdgcn_rcpf(red_s[h * 64 + jl]);
    float hg[HID];
#pragma unroll
    for (int r = 0; r < HID; r++)
        hg[r] = red_s[(HEADS + r) * 64 + jl] * inv[r >> 3] + bias_g[r];
#pragma unroll
    for (int hh = 0; hh < 8; hh++) {
        int h = tg * 8 + hh;
        float si = 0.f, sj = 0.f;
#pragma unroll
        for (int d = 0; d < HID; d++) {
            si = fmaf(hg[d], W1[h * 2 * HID + d], si);
            sj = fmaf(hg[d], W1[h * 2 * HID + HID + d], sj);
        }
        ws[OFF_TIT + ((size_t)b * HID + h) * Nq + n] = si;       // coalesced
        ws[OFF_TJB + ((size_t)b * HID + h) * Nq + n] = sj + b1[h];
    }
}

// ---- k3: pairwise score. grid (32, Bq), block 512. ----
__global__ __launch_bounds__(512) void k3_score(const float* __restrict__ w2_p,
                                                const float* __restrict__ b2_p,
                                                const float* __restrict__ ws,
                                                float* __restrict__ out) {
    int b = blockIdx.y;
    int i0 = blockIdx.x * 16;
    int j = threadIdx.x;
    __shared__ float tis[HID * 16];  // [h][ii]
    {
        int h = threadIdx.x >> 4, ii = threadIdx.x & 15;
        tis[threadIdx.x] = ws[OFF_TIT + ((size_t)b * HID + h) * Nq + i0 + ii];
    }
    float tjb[HID];
#pragma unroll
    for (int h = 0; h < HID; h++) tjb[h] = ws[OFF_TJB + ((size_t)b * HID + h) * Nq + j];
    float w2l[HID];
#pragma unroll
    for (int h = 0; h < HID; h++) w2l[h] = w2_p[h];
    float b2 = b2_p[0];
    __syncthreads();
    const uint64_t* packed = (const uint64_t*)(ws + OFF_PACK);
    for (int ii = 0; ii < 16; ii++) {
        int i = i0 + ii;
        uint64_t m = packed[((size_t)b * Nq + i) * (Nq / 64) + (j >> 6)];
        bool on = (((m >> (j & 63)) & 1ull) != 0) && (i != j);
        float s = b2;
#pragma unroll
        for (int h = 0; h < HID; h++) {
            float t = tis[h * 16 + ii] + tjb[h];  // broadcast LDS read
            t = t > 0.f ? t : 0.f;
            s = fmaf(t, w2l[h], s);
        }
        float score = __builtin_amdgcn_rcpf(1.f + __expf(-s));
        out[((size_t)b * Nq + i) * Nq + j] = on ? score : 0.f;
    }
}

extern "C" void kernel_launch(void* const* d_in, const int* in_sizes, int n_in,
                              void* d_out, int out_size, void* d_ws, size_t ws_size,
                              hipStream_t stream) {
    const float* x       = (const float*)d_in[0];
    const int*   adj     = (const int*)d_in[1];
    const float* Wp      = (const float*)d_in[2];
    const float* bp      = (const float*)d_in[3];
    const float* Wg      = (const float*)d_in[4];
    const float* att_src = (const float*)d_in[5];
    const float* att_dst = (const float*)d_in[6];
    const float* bias_g  = (const float*)d_in[7];
    const float* W1      = (const float*)d_in[8];
    const float* b1      = (const float*)d_in[9];
    const float* w2      = (const float*)d_in[10];
    const float* b2      = (const float*)d_in[11];
    float* out = (float*)d_out;
    float* ws = (float*)d_ws;

    auto need = [](int P) {
        return (size_t)(OFF_PART + (size_t)P * Bq * NR * Nq) * sizeof(float);
    };

    k0_node<<<dim3(1024), dim3(256), 0, stream>>>(x, Wp, bp, Wg, att_src, att_dst, ws);

    if (ws_size >= need(16)) {
        k1_aggregate<32><<<dim3(16, 2, Bq), dim3(256), 0, stream>>>(adj, ws);
        k2_fused<16><<<dim3(8, Bq), dim3(256), 0, stream>>>(bias_g, W1, b1, ws);
    } else if (ws_size >= need(8)) {
        k1_aggregate<64><<<dim3(8, 2, Bq), dim3(256), 0, stream>>>(adj, ws);
        k2_fused<8><<<dim3(8, Bq), dim3(256), 0, stream>>>(bias_g, W1, b1, ws);
    } else if (ws_size >= need(4)) {
        k1_aggregate<128><<<dim3(4, 2, Bq), dim3(256), 0, stream>>>(adj, ws);
        k2_fused<4><<<dim3(8, Bq), dim3(256), 0, stream>>>(bias_g, W1, b1, ws);
    } else {
        k1_aggregate<256><<<dim3(2, 2, Bq), dim3(256), 0, stream>>>(adj, ws);
        k2_fused<2><<<dim3(8, Bq), dim3(256), 0, stream>>>(bias_g, W1, b1, ws);
    }

    k3_score<<<dim3(32, Bq), dim3(512), 0, stream>>>(w2, b2, ws, out);
}